// Round 13
// baseline (191.339 us; speedup 1.0000x reference)
//
#include <hip/hip_runtime.h>

// DISCO S2 conv, equiangular 360x720 -> 180x360, K=3, B*C=128.
// out[bc, k*180+t, p] = sum_{e in seg(k,t)} val[e]*qw[lat[e]] * x[bc, lat[e], (lon[e]-2p-2) mod 720]
//
// Round-13: R11 structure + bank-conflict-free LDS layout.
//  - Hot-loop reads had an 8-way bank conflict: PB=3 float4 slots = 12-dword
//    lane stride, 12l mod 32 has period 8. Fix: split slots into two 8-B
//    half-planes (L=ch01, H=ch23) and XOR-swizzle the byte address
//    (addr ^= (addr>>4)&8, i.e. flip slot-bit0 on slot-bit4). Lane stride 3
//    slots then hits all 16 bank pairs and the swizzle breaks the l/l+16
//    alias -> 2-way max (free). Same swizzle at write & read.
//  - everything else identical to round 11: (bcg,t,k) k-split grid, T14
//    async staging, wave-parallel run builder, PB=3 register window,
//    v_pk_fma_f32, pole constant-val rowsum collapse, poles-first dispatch.

#define NLAT_IN  360
#define NLON_IN  720
#define NLAT_OUT 180
#define NLON_OUT 360
#define KSIZE    3
#define NSEG     (KSIZE * NLAT_OUT)    // 540
#define CHW      (NLAT_IN * NLON_IN)   // 259200
#define BCTOT    128
#define G        4
#define NBCG     (BCTOT / G)           // 32
#define MAXR     2
#define PH       10
#define NTHREADS 256
#define SLOTS    432                   // 360 + 72 wrap mirror
#define MIRROR   (SLOTS - NLON_OUT)    // 72
#define ROWB     (SLOTS * 8)           // 3456 B per half-plane row-parity plane

typedef float v2f __attribute__((ext_vector_type(2)));

__device__ __forceinline__ void PKF(v2f& a, v2f x, v2f c) {
    asm("v_pk_fma_f32 %0, %1, %2, %0" : "+v"(a) : "v"(x), "v"(c));
}
__device__ __forceinline__ unsigned swz8(unsigned a) { return a ^ ((a >> 4) & 8u); }

// ---------------- prep ----------------

__global__ void prep1_kernel(const int* __restrict__ seg, const int* __restrict__ lat,
                             const float* __restrict__ val, int nnz,
                             int* __restrict__ ptrh, int* __restrict__ hbase,
                             int* __restrict__ hlast, int* __restrict__ flags) {
    int idx = blockIdx.x * blockDim.x + threadIdx.x;
    if (idx >= NSEG * PH) return;
    int s = idx / PH, j = idx - s * PH;
    int lo = 0, hi = nnz;
    while (lo < hi) { int m = (lo + hi) >> 1; if (seg[m] < s) lo = m + 1; else hi = m; }
    int e0 = lo;
    lo = e0; hi = nnz;
    while (lo < hi) { int m = (lo + hi) >> 1; if (seg[m] < s + 1) lo = m + 1; else hi = m; }
    int e1 = lo;
    if (e0 >= e1) {
        ptrh[idx] = e0; flags[idx] = 0;
        if (j == 0) { hbase[s] = 1 << 28; hlast[s] = -(1 << 28); }
        return;
    }
    int hb = lat[e0];
    if (j == 0) { hbase[s] = hb; hlast[s] = lat[e1 - 1]; }
    int a;
    { int tg = hb + j; lo = e0; hi = e1;
      while (lo < hi) { int m = (lo + hi) >> 1; if (lat[m] < tg) lo = m + 1; else hi = m; }
      a = lo; }
    ptrh[idx] = a;
    int f = 0;
    if (j < PH - 1) {
        int tg = hb + j + 1; lo = a; hi = e1;
        while (lo < hi) { int m = (lo + hi) >> 1; if (lat[m] < tg) lo = m + 1; else hi = m; }
        int b = lo;
        if (b - a == NLON_IN) {
            float v0 = val[a], v1 = val[a + 240], v2 = val[a + 480];
            float d = fmaxf(fabsf(v0 - v1), fmaxf(fabsf(v0 - v2), fabsf(v1 - v2)));
            f = (d < 1e-5f) ? 1 : 0;
        }
    }
    flags[idx] = f;
}

__global__ void cf_kernel(const int* __restrict__ lat, const float* __restrict__ val,
                          const float* __restrict__ qw, int nnz, float* __restrict__ cfb) {
    int e = blockIdx.x * blockDim.x + threadIdx.x;
    if (e < nnz) cfb[e] = val[e] * qw[lat[e]];
}

// wave-parallel run builder: one wave per (s,j) row; 64-entry chunks.
__global__ void runs_kernel(const int* __restrict__ lon, const int* __restrict__ ptrh,
                            const int* __restrict__ flags,
                            int* __restrict__ runcnt, uint2* __restrict__ runslab) {
    const int idx  = blockIdx.x * 4 + (threadIdx.x >> 6);
    if (idx >= NSEG * PH) return;
    const int lane = threadIdx.x & 63;
    const int j = idx % PH;
    int runbase = 0;
    if (j < PH - 1) {
        const int a = ptrh[idx], b = ptrh[idx + 1];
        if (b > a && !flags[idx]) {
            for (int c = a; c < b; c += 64) {
                const int e = c + lane;
                const bool active = e < b;
                const int w   = active ? lon[e] : 0;
                const int wm1 = (active && e > a) ? lon[e - 1] : -99;
                const bool isStart = active && (lane == 0 || w != wm1 + 1);
                const unsigned long long mask = __ballot(isStart);
                if (isStart) {
                    const int cnt = min(64, b - c);
                    unsigned long long hv = (mask >> lane) >> 1;
                    const int len = hv ? __ffsll((long long)hv) : (cnt - lane);
                    const int cidx = __popcll(mask & ((1ull << lane) - 1ull));
                    const int s0 = ((w >> 1) + NLON_OUT - 1) % NLON_OUT;
                    runslab[a + runbase + cidx] = make_uint2(
                        (unsigned)e, (unsigned)(s0 | ((w & 1) << 9) | (len << 11)));
                }
                runbase += __popcll(mask);
            }
        }
    }
    if (lane == 0) runcnt[idx] = runbase;
}

// ---------------- main ----------------

__global__ __launch_bounds__(NTHREADS) void disco_kernel(
    const float* __restrict__ x,
    const float* __restrict__ cfb,
    const uint2* __restrict__ runslab,
    const int*   __restrict__ runcnt,
    const int*   __restrict__ ptrh,
    const int*   __restrict__ hbase,
    const int*   __restrict__ hlast,
    const int*   __restrict__ flags,
    float*       __restrict__ out)
{
    __shared__ v2f ldsL[MAXR * 2][SLOTS];      // ch0,ch1: 13,824 B
    __shared__ v2f ldsH[MAXR * 2][SLOTS];      // ch2,ch3: 13,824 B
    __shared__ v2f accbuf[120][6];             //  5,760 B  -> 33,408 B total

    const int tid      = threadIdx.x;
    const int lane     = tid & 63;
    const int wpair    = tid >> 7;
    const int pairlane = tid & 127;
    const int pid      = (pairlane < 120) ? pairlane : pairlane - 120;
    const int p0       = 3 * pid;
    const int bc0      = blockIdx.x * G;
    const int ty       = blockIdx.y;
    const int t        = (ty & 1) ? (NLAT_OUT - 1 - (ty >> 1)) : (ty >> 1); // poles first
    const int s        = blockIdx.z * NLAT_OUT + t;
    const int hb = hbase[s], hl = hlast[s];    // empty: hb > hl

    v2f a0l = {0.f, 0.f}, a0h = a0l, a1l = a0l, a1h = a0l, a2l = a0l, a2h = a0l;
    const char* lbL = (const char*)&ldsL[0][0];
    const char* lbH = (const char*)&ldsH[0][0];
    char* lbLw = (char*)&ldsL[0][0];
    char* lbHw = (char*)&ldsH[0][0];

    float2 sv0[4], sv1[4], sv2[4];             // T14 staging registers
    const float* xb = x + (size_t)bc0 * CHW;

#define LOADW(R0)                                                              \
    {                                                                          \
        {   const int idx_ = tid;                                              \
            const int rr_ = idx_ >= 360;                                       \
            const int m_  = idx_ - 360 * rr_;                                  \
            const int row_ = min((R0) + rr_, hl);                              \
            const float* xr_ = xb + (size_t)row_ * NLON_IN + 2 * m_;           \
            sv0[0] = *(const float2*)(xr_);                                    \
            sv0[1] = *(const float2*)(xr_ + CHW);                              \
            sv0[2] = *(const float2*)(xr_ + 2 * CHW);                          \
            sv0[3] = *(const float2*)(xr_ + 3 * CHW);                          \
        }                                                                      \
        {   const int idx_ = tid + 256;                                        \
            const int rr_ = idx_ >= 360;                                       \
            const int m_  = idx_ - 360 * rr_;                                  \
            const int row_ = min((R0) + rr_, hl);                              \
            const float* xr_ = xb + (size_t)row_ * NLON_IN + 2 * m_;           \
            sv1[0] = *(const float2*)(xr_);                                    \
            sv1[1] = *(const float2*)(xr_ + CHW);                              \
            sv1[2] = *(const float2*)(xr_ + 2 * CHW);                          \
            sv1[3] = *(const float2*)(xr_ + 3 * CHW);                          \
        }                                                                      \
        if (tid < 208) {                                                       \
            const int m_  = tid + 512 - 360;                                   \
            const int row_ = min((R0) + 1, hl);                                \
            const float* xr_ = xb + (size_t)row_ * NLON_IN + 2 * m_;           \
            sv2[0] = *(const float2*)(xr_);                                    \
            sv2[1] = *(const float2*)(xr_ + CHW);                              \
            sv2[2] = *(const float2*)(xr_ + 2 * CHW);                          \
            sv2[3] = *(const float2*)(xr_ + 3 * CHW);                          \
        }                                                                      \
    }

#define WRITE1(SV, RR, M)                                                      \
    {                                                                          \
        const unsigned bE_ = (unsigned)(2 * (RR)) * ROWB + ((unsigned)(M) << 3); \
        const unsigned bO_ = bE_ + ROWB;                                       \
        const unsigned sE_ = swz8(bE_), sO_ = swz8(bO_);                       \
        *(v2f*)(lbLw + sE_) = (v2f){SV[0].x, SV[1].x};                         \
        *(v2f*)(lbHw + sE_) = (v2f){SV[2].x, SV[3].x};                         \
        *(v2f*)(lbLw + sO_) = (v2f){SV[0].y, SV[1].y};                         \
        *(v2f*)(lbHw + sO_) = (v2f){SV[2].y, SV[3].y};                         \
        if ((M) < MIRROR) {                                                    \
            const unsigned bE2_ = bE_ + (NLON_OUT << 3);                       \
            const unsigned bO2_ = bO_ + (NLON_OUT << 3);                       \
            const unsigned sE2_ = swz8(bE2_), sO2_ = swz8(bO2_);               \
            *(v2f*)(lbLw + sE2_) = (v2f){SV[0].x, SV[1].x};                    \
            *(v2f*)(lbHw + sE2_) = (v2f){SV[2].x, SV[3].x};                    \
            *(v2f*)(lbLw + sO2_) = (v2f){SV[0].y, SV[1].y};                    \
            *(v2f*)(lbHw + sO2_) = (v2f){SV[2].y, SV[3].y};                    \
        }                                                                      \
    }

#define WRITEW()                                                               \
    {                                                                          \
        { const int idx_ = tid;       const int rr_ = idx_ >= 360;             \
          const int m_ = idx_ - 360 * rr_; WRITE1(sv0, rr_, m_); }             \
        { const int idx_ = tid + 256; const int rr_ = idx_ >= 360;             \
          const int m_ = idx_ - 360 * rr_; WRITE1(sv1, rr_, m_); }             \
        if (tid < 208) { const int m_ = tid + 512 - 360; WRITE1(sv2, 1, m_); } \
    }

    if (hb <= hl) {
        LOADW(hb);                              // prologue: first window in flight
        for (int r0 = hb; r0 <= hl; r0 += MAXR) {
            const int rn = min(MAXR, hl - r0 + 1);
            __syncthreads();                    // readers of previous window done
            WRITEW();                           // vmcnt wait hidden under prev compute
            if (r0 + MAXR <= hl) LOADW(r0 + MAXR);
            __syncthreads();                    // LDS ready
            // ---- compute window ----
            for (int r = 0; r < rn; ++r) {
                const int j = (r0 + r) - hb;
                if (j < 0 || j >= PH - 1) continue;
                if ((j & 1) != wpair) continue;  // wave-uniform
                const int idx = s * PH + j;
                const int a = ptrh[idx], b = ptrh[idx + 1];
                if (a >= b) continue;
                const int rp0 = (j & 1) * 2;
                if (flags[idx]) {                // constant-val full row: cf*rowsum
                    v2f vl = {0.f, 0.f}, vh = vl;
                    for (int m = lane; m < NLON_OUT; m += 64) {
                        const unsigned bE = swz8((unsigned)rp0 * ROWB + ((unsigned)m << 3));
                        const unsigned bO = swz8((unsigned)(rp0 + 1) * ROWB + ((unsigned)m << 3));
                        vl += *(const v2f*)(lbL + bE) + *(const v2f*)(lbL + bO);
                        vh += *(const v2f*)(lbH + bE) + *(const v2f*)(lbH + bO);
                    }
#pragma unroll
                    for (int o = 32; o >= 1; o >>= 1) {
                        vl.x += __shfl_xor(vl.x, o); vl.y += __shfl_xor(vl.y, o);
                        vh.x += __shfl_xor(vh.x, o); vh.y += __shfl_xor(vh.y, o);
                    }
                    const float cf = cfb[a];
                    const v2f c = (v2f){cf, cf};
                    PKF(a0l, vl, c); PKF(a0h, vh, c);
                    PKF(a1l, vl, c); PKF(a1h, vh, c);
                    PKF(a2l, vl, c); PKF(a2h, vh, c);
                    continue;
                }
                const int rc = runcnt[idx];
                for (int rr = 0; rr < rc; ++rr) {
                    const uint2 R = runslab[a + rr];
                    const int e0  = __builtin_amdgcn_readfirstlane((int)R.x);
                    const int y   = __builtin_amdgcn_readfirstlane((int)R.y);
                    const int s0A = y & 511;
                    const int odd = (y >> 9) & 1;
                    const int len = y >> 11;
                    int qA = s0A - p0 - 2; qA += (qA >> 31) & NLON_OUT;
                    const unsigned baA = (unsigned)(rp0 + odd) * ROWB + ((unsigned)qA << 3);
                    const unsigned baB = (unsigned)(rp0 + (odd ^ 1)) * ROWB
                                       + ((unsigned)(qA + odd) << 3);
                    const float* cfp = cfb + e0;
                    int i = 0;
                    if (len >= 8) {
                        unsigned w0 = swz8(baA), w1 = swz8(baA + 8), w2 = swz8(baA + 16);
                        v2f A0l = *(const v2f*)(lbL + w0), A0h = *(const v2f*)(lbH + w0);
                        v2f A1l = *(const v2f*)(lbL + w1), A1h = *(const v2f*)(lbH + w1);
                        v2f A2l = *(const v2f*)(lbL + w2), A2h = *(const v2f*)(lbH + w2);
                        w0 = swz8(baB); w1 = swz8(baB + 8); w2 = swz8(baB + 16);
                        v2f B0l = *(const v2f*)(lbL + w0), B0h = *(const v2f*)(lbH + w0);
                        v2f B1l = *(const v2f*)(lbL + w1), B1h = *(const v2f*)(lbH + w1);
                        v2f B2l = *(const v2f*)(lbL + w2), B2h = *(const v2f*)(lbH + w2);
                        v2f A3l, A3h, B3l, B3h;
                        unsigned soA = baA + 24;
                        unsigned soB = baB + 24;
                        for (; i + 8 <= len; i += 8) {
                            float cs; v2f c; unsigned sw;
                            sw = swz8(soA); soA += 8;
                            A3l = *(const v2f*)(lbL + sw); A3h = *(const v2f*)(lbH + sw);
                            cs = cfp[i + 0]; c = (v2f){cs, cs};
                            PKF(a2l, A0l, c); PKF(a2h, A0h, c);
                            PKF(a1l, A1l, c); PKF(a1h, A1h, c);
                            PKF(a0l, A2l, c); PKF(a0h, A2h, c);
                            sw = swz8(soB); soB += 8;
                            B3l = *(const v2f*)(lbL + sw); B3h = *(const v2f*)(lbH + sw);
                            cs = cfp[i + 1]; c = (v2f){cs, cs};
                            PKF(a2l, B0l, c); PKF(a2h, B0h, c);
                            PKF(a1l, B1l, c); PKF(a1h, B1h, c);
                            PKF(a0l, B2l, c); PKF(a0h, B2h, c);
                            sw = swz8(soA); soA += 8;
                            A0l = *(const v2f*)(lbL + sw); A0h = *(const v2f*)(lbH + sw);
                            cs = cfp[i + 2]; c = (v2f){cs, cs};
                            PKF(a2l, A1l, c); PKF(a2h, A1h, c);
                            PKF(a1l, A2l, c); PKF(a1h, A2h, c);
                            PKF(a0l, A3l, c); PKF(a0h, A3h, c);
                            sw = swz8(soB); soB += 8;
                            B0l = *(const v2f*)(lbL + sw); B0h = *(const v2f*)(lbH + sw);
                            cs = cfp[i + 3]; c = (v2f){cs, cs};
                            PKF(a2l, B1l, c); PKF(a2h, B1h, c);
                            PKF(a1l, B2l, c); PKF(a1h, B2h, c);
                            PKF(a0l, B3l, c); PKF(a0h, B3h, c);
                            sw = swz8(soA); soA += 8;
                            A1l = *(const v2f*)(lbL + sw); A1h = *(const v2f*)(lbH + sw);
                            cs = cfp[i + 4]; c = (v2f){cs, cs};
                            PKF(a2l, A2l, c); PKF(a2h, A2h, c);
                            PKF(a1l, A3l, c); PKF(a1h, A3h, c);
                            PKF(a0l, A0l, c); PKF(a0h, A0h, c);
                            sw = swz8(soB); soB += 8;
                            B1l = *(const v2f*)(lbL + sw); B1h = *(const v2f*)(lbH + sw);
                            cs = cfp[i + 5]; c = (v2f){cs, cs};
                            PKF(a2l, B2l, c); PKF(a2h, B2h, c);
                            PKF(a1l, B3l, c); PKF(a1h, B3h, c);
                            PKF(a0l, B0l, c); PKF(a0h, B0h, c);
                            sw = swz8(soA); soA += 8;
                            A2l = *(const v2f*)(lbL + sw); A2h = *(const v2f*)(lbH + sw);
                            cs = cfp[i + 6]; c = (v2f){cs, cs};
                            PKF(a2l, A3l, c); PKF(a2h, A3h, c);
                            PKF(a1l, A0l, c); PKF(a1h, A0h, c);
                            PKF(a0l, A1l, c); PKF(a0h, A1h, c);
                            sw = swz8(soB); soB += 8;
                            B2l = *(const v2f*)(lbL + sw); B2h = *(const v2f*)(lbH + sw);
                            cs = cfp[i + 7]; c = (v2f){cs, cs};
                            PKF(a2l, B3l, c); PKF(a2h, B3h, c);
                            PKF(a1l, B0l, c); PKF(a1h, B0h, c);
                            PKF(a0l, B1l, c); PKF(a0h, B1h, c);
                        }
                    }
                    for (; i < len; ++i) {       // tail / short runs
                        const int m_ = i >> 1;
                        const unsigned bp = ((i & 1) ? baB : baA) + ((unsigned)m_ << 3);
                        const unsigned u0 = swz8(bp), u1 = swz8(bp + 8), u2 = swz8(bp + 16);
                        const float cs = cfp[i]; const v2f c = (v2f){cs, cs};
                        const v2f w0l = *(const v2f*)(lbL + u0), w0h = *(const v2f*)(lbH + u0);
                        const v2f w1l = *(const v2f*)(lbL + u1), w1h = *(const v2f*)(lbH + u1);
                        const v2f w2l = *(const v2f*)(lbL + u2), w2h = *(const v2f*)(lbH + u2);
                        PKF(a2l, w0l, c); PKF(a2h, w0h, c);
                        PKF(a1l, w1l, c); PKF(a1h, w1h, c);
                        PKF(a0l, w2l, c); PKF(a0h, w2h, c);
                    }
                }
            }
        }
    }

    // ---- combine pair-1 into pair-0, store ----
    __syncthreads();
    if (wpair == 1 && pairlane < 120) {
        accbuf[pid][0] = a0l; accbuf[pid][1] = a0h;
        accbuf[pid][2] = a1l; accbuf[pid][3] = a1h;
        accbuf[pid][4] = a2l; accbuf[pid][5] = a2h;
    }
    __syncthreads();
    if (wpair == 0 && pairlane < 120) {
        a0l += accbuf[pid][0]; a0h += accbuf[pid][1];
        a1l += accbuf[pid][2]; a1h += accbuf[pid][3];
        a2l += accbuf[pid][4]; a2h += accbuf[pid][5];
        const size_t cs_ = (size_t)NSEG * NLON_OUT;
        const size_t ob  = ((size_t)bc0 * NSEG + s) * NLON_OUT + p0;
        out[ob]              = a0l.x; out[ob + 1]              = a1l.x; out[ob + 2]              = a2l.x;
        out[ob + cs_]        = a0l.y; out[ob + cs_ + 1]        = a1l.y; out[ob + cs_ + 2]        = a2l.y;
        out[ob + 2 * cs_]    = a0h.x; out[ob + 2 * cs_ + 1]    = a1h.x; out[ob + 2 * cs_ + 2]    = a2h.x;
        out[ob + 3 * cs_]    = a0h.y; out[ob + 3 * cs_ + 1]    = a1h.y; out[ob + 3 * cs_ + 2]    = a2h.y;
    }
#undef LOADW
#undef WRITEW
#undef WRITE1
}

// ---------------- fallback (tiny ws) ----------------

__global__ void segptr_kernel(const int* __restrict__ seg, int nnz, int* __restrict__ ptr) {
    int s = blockIdx.x * blockDim.x + threadIdx.x;
    if (s > NSEG) return;
    if (s == NSEG) { ptr[NSEG] = nnz; return; }
    int lo = 0, hi = nnz;
    while (lo < hi) { int m = (lo + hi) >> 1; if (seg[m] < s) lo = m + 1; else hi = m; }
    ptr[s] = lo;
}

__global__ __launch_bounds__(384) void disco_simple_kernel(
    const float* __restrict__ x, const float* __restrict__ qw,
    const int* __restrict__ lat, const int* __restrict__ lon,
    const float* __restrict__ val, const int* __restrict__ ptr,
    float* __restrict__ out)
{
    const int p = threadIdx.x;
    if (p >= NLON_OUT) return;
    const int kt = blockIdx.x, bc0 = blockIdx.y * 8;
    const int e0 = ptr[kt], e1 = ptr[kt + 1];
    float acc[8];
#pragma unroll
    for (int g = 0; g < 8; ++g) acc[g] = 0.0f;
    const int pw = 2 * p + 2;
    const float* xb = x + (size_t)bc0 * CHW;
    for (int e = e0; e < e1; ++e) {
        const int h = lat[e], w = lon[e];
        const float cf = val[e] * qw[h];
        int col = w - pw; if (col < 0) col += NLON_IN;
        const float* src = xb + h * NLON_IN + col;
#pragma unroll
        for (int g = 0; g < 8; ++g) acc[g] = fmaf(cf, src[(size_t)g * CHW], acc[g]);
    }
    const size_t ob = ((size_t)bc0 * NSEG + kt) * NLON_OUT + p;
#pragma unroll
    for (int g = 0; g < 8; ++g) out[ob + (size_t)g * NSEG * NLON_OUT] = acc[g];
}

// ---------------- launcher ----------------

extern "C" void kernel_launch(void* const* d_in, const int* in_sizes, int n_in,
                              void* d_out, int out_size, void* d_ws, size_t ws_size,
                              hipStream_t stream)
{
    const float* x   = (const float*)d_in[0];   // [2,64,360,720] f32
    const float* qw  = (const float*)d_in[1];   // [360,1] f32
    const int*   seg = (const int*)  d_in[2];   // [nnz] i32 sorted asc
    const int*   lat = (const int*)  d_in[3];
    const int*   lon = (const int*)  d_in[4];
    const float* val = (const float*)d_in[5];
    const int    nnz = in_sizes[2];
    const int    nnzpad = (nnz + 3) & ~3;

    char* w = (char*)d_ws;
    size_t off = 0;
    int* ptrh   = (int*)(w + off); off += (size_t)NSEG * PH * 4;   // 21600
    int* hbase  = (int*)(w + off); off += NSEG * 4;
    int* hlast  = (int*)(w + off); off += NSEG * 4;
    int* flags  = (int*)(w + off); off += (size_t)NSEG * PH * 4;
    int* runcnt = (int*)(w + off); off += (size_t)NSEG * PH * 4;
    float* cfb  = (float*)(w + off); off += (size_t)nnzpad * 4;
    off = (off + 7) & ~(size_t)7;
    uint2* runslab = (uint2*)(w + off); off += (size_t)nnz * 8;

    if (ws_size < off) {                         // tiny ws: slow-but-correct path
        int* ptr = (int*)d_ws;
        segptr_kernel<<<(NSEG + 1 + 255) / 256, 256, 0, stream>>>(seg, nnz, ptr);
        dim3 grid(NSEG, BCTOT / 8);
        disco_simple_kernel<<<grid, 384, 0, stream>>>(x, qw, lat, lon, val, ptr,
                                                      (float*)d_out);
        return;
    }

    prep1_kernel<<<(NSEG * PH + 255) / 256, 256, 0, stream>>>(seg, lat, val, nnz,
                                                              ptrh, hbase, hlast, flags);
    cf_kernel<<<(nnz + 255) / 256, 256, 0, stream>>>(lat, val, qw, nnz, cfb);
    runs_kernel<<<(NSEG * PH + 3) / 4, 256, 0, stream>>>(lon, ptrh, flags,
                                                         runcnt, runslab);

    dim3 grid(NBCG, NLAT_OUT, KSIZE);
    disco_kernel<<<grid, NTHREADS, 0, stream>>>(x, cfb, runslab, runcnt,
                                                ptrh, hbase, hlast, flags,
                                                (float*)d_out);
}

// Round 14
// 151.996 us; speedup vs baseline: 1.2588x; 1.2588x over previous
//
#include <hip/hip_runtime.h>

// DISCO S2 conv, equiangular 360x720 -> 180x360, K=3, B*C=128.
// out[bc, k*180+t, p] = sum_{e in seg(k,t)} val[e]*qw[lat[e]] * x[bc, lat[e], (lon[e]-2p-2) mod 720]
//
// Round-14: exact round-11 structure (best known, 153 us) + LDS diet for occupancy.
//  - R12/R13 both regressed (k-merge -> VGPR+serialization; swizzle -> created
//    conflicts). Reverted. R11 hot reads are conflict-free (quad stride 3 mod 8
//    covers all 8 quads).
//  - accbuf overlaid on ldsx (epilogue-only, after barrier) and wrap mirror
//    shrunk 72->40 slots (max read-ahead ~qA+35): LDS 33,792 -> 25,600 B
//    -> 6 blocks/CU = 24 waves/CU (was 4 blocks/16 waves).
//  - everything else identical to round 11: (bcg,t,k) k-split grid, T14 async
//    staging (issue-early/write-late), wave-parallel run builder, PB=3
//    register window, v_pk_fma_f32, pole constant-val rowsum collapse,
//    poles-first dispatch.

#define NLAT_IN  360
#define NLON_IN  720
#define NLAT_OUT 180
#define NLON_OUT 360
#define KSIZE    3
#define NSEG     (KSIZE * NLAT_OUT)    // 540
#define CHW      (NLAT_IN * NLON_IN)   // 259200
#define BCTOT    128
#define G        4
#define NBCG     (BCTOT / G)           // 32
#define MAXR     2
#define PH       10
#define NTHREADS 256
#define SLOTS    400                   // 360 + 40 wrap mirror (max reach qA+35)
#define MIRROR   (SLOTS - NLON_OUT)    // 40
#define ROWB     (SLOTS * 16)          // 6400 B per row-parity plane

typedef float v2f __attribute__((ext_vector_type(2)));

__device__ __forceinline__ void PKF(v2f& a, v2f x, v2f c) {
    asm("v_pk_fma_f32 %0, %1, %2, %0" : "+v"(a) : "v"(x), "v"(c));
}

// ---------------- prep ----------------

__global__ void prep1_kernel(const int* __restrict__ seg, const int* __restrict__ lat,
                             const float* __restrict__ val, int nnz,
                             int* __restrict__ ptrh, int* __restrict__ hbase,
                             int* __restrict__ hlast, int* __restrict__ flags) {
    int idx = blockIdx.x * blockDim.x + threadIdx.x;
    if (idx >= NSEG * PH) return;
    int s = idx / PH, j = idx - s * PH;
    int lo = 0, hi = nnz;
    while (lo < hi) { int m = (lo + hi) >> 1; if (seg[m] < s) lo = m + 1; else hi = m; }
    int e0 = lo;
    lo = e0; hi = nnz;
    while (lo < hi) { int m = (lo + hi) >> 1; if (seg[m] < s + 1) lo = m + 1; else hi = m; }
    int e1 = lo;
    if (e0 >= e1) {
        ptrh[idx] = e0; flags[idx] = 0;
        if (j == 0) { hbase[s] = 1 << 28; hlast[s] = -(1 << 28); }
        return;
    }
    int hb = lat[e0];
    if (j == 0) { hbase[s] = hb; hlast[s] = lat[e1 - 1]; }
    int a;
    { int tg = hb + j; lo = e0; hi = e1;
      while (lo < hi) { int m = (lo + hi) >> 1; if (lat[m] < tg) lo = m + 1; else hi = m; }
      a = lo; }
    ptrh[idx] = a;
    int f = 0;
    if (j < PH - 1) {
        int tg = hb + j + 1; lo = a; hi = e1;
        while (lo < hi) { int m = (lo + hi) >> 1; if (lat[m] < tg) lo = m + 1; else hi = m; }
        int b = lo;
        if (b - a == NLON_IN) {
            float v0 = val[a], v1 = val[a + 240], v2 = val[a + 480];
            float d = fmaxf(fabsf(v0 - v1), fmaxf(fabsf(v0 - v2), fabsf(v1 - v2)));
            f = (d < 1e-5f) ? 1 : 0;
        }
    }
    flags[idx] = f;
}

__global__ void cf_kernel(const int* __restrict__ lat, const float* __restrict__ val,
                          const float* __restrict__ qw, int nnz, float* __restrict__ cfb) {
    int e = blockIdx.x * blockDim.x + threadIdx.x;
    if (e < nnz) cfb[e] = val[e] * qw[lat[e]];
}

// wave-parallel run builder: one wave per (s,j) row; 64-entry chunks.
__global__ void runs_kernel(const int* __restrict__ lon, const int* __restrict__ ptrh,
                            const int* __restrict__ flags,
                            int* __restrict__ runcnt, uint2* __restrict__ runslab) {
    const int idx  = blockIdx.x * 4 + (threadIdx.x >> 6);
    if (idx >= NSEG * PH) return;
    const int lane = threadIdx.x & 63;
    const int j = idx % PH;
    int runbase = 0;
    if (j < PH - 1) {
        const int a = ptrh[idx], b = ptrh[idx + 1];
        if (b > a && !flags[idx]) {
            for (int c = a; c < b; c += 64) {
                const int e = c + lane;
                const bool active = e < b;
                const int w   = active ? lon[e] : 0;
                const int wm1 = (active && e > a) ? lon[e - 1] : -99;
                const bool isStart = active && (lane == 0 || w != wm1 + 1);
                const unsigned long long mask = __ballot(isStart);
                if (isStart) {
                    const int cnt = min(64, b - c);
                    unsigned long long hv = (mask >> lane) >> 1;
                    const int len = hv ? __ffsll((long long)hv) : (cnt - lane);
                    const int cidx = __popcll(mask & ((1ull << lane) - 1ull));
                    const int s0 = ((w >> 1) + NLON_OUT - 1) % NLON_OUT;
                    runslab[a + runbase + cidx] = make_uint2(
                        (unsigned)e, (unsigned)(s0 | ((w & 1) << 9) | (len << 11)));
                }
                runbase += __popcll(mask);
            }
        }
    }
    if (lane == 0) runcnt[idx] = runbase;
}

// ---------------- main ----------------

__global__ __launch_bounds__(NTHREADS) void disco_kernel(
    const float* __restrict__ x,
    const float* __restrict__ cfb,
    const uint2* __restrict__ runslab,
    const int*   __restrict__ runcnt,
    const int*   __restrict__ ptrh,
    const int*   __restrict__ hbase,
    const int*   __restrict__ hlast,
    const int*   __restrict__ flags,
    float*       __restrict__ out)
{
    __shared__ float4 ldsx[MAXR * 2][SLOTS];   // 25,600 B -> 6 blocks/CU
    v2f (*accbuf)[6] = (v2f(*)[6])&ldsx[0][0]; // epilogue overlay (after barrier)

    const int tid      = threadIdx.x;
    const int lane     = tid & 63;
    const int wpair    = tid >> 7;             // 0: waves 0-1, 1: waves 2-3
    const int pairlane = tid & 127;
    const int pid      = (pairlane < 120) ? pairlane : pairlane - 120;
    const int p0       = 3 * pid;
    const int bc0      = blockIdx.x * G;
    const int ty       = blockIdx.y;
    const int t        = (ty & 1) ? (NLAT_OUT - 1 - (ty >> 1)) : (ty >> 1); // poles first
    const int s        = blockIdx.z * NLAT_OUT + t;
    const int hb = hbase[s], hl = hlast[s];    // empty: hb > hl

    v2f a0l = {0.f, 0.f}, a0h = a0l, a1l = a0l, a1h = a0l, a2l = a0l, a2h = a0l;
    const char* lb = (const char*)&ldsx[0][0];

    float2 sv0[4], sv1[4], sv2[4];             // T14 staging registers
    const float* xb = x + (size_t)bc0 * CHW;

#define LOADW(R0)                                                              \
    {                                                                          \
        {   const int idx_ = tid;                                              \
            const int rr_ = idx_ >= 360;                                       \
            const int m_  = idx_ - 360 * rr_;                                  \
            const int row_ = min((R0) + rr_, hl);                              \
            const float* xr_ = xb + (size_t)row_ * NLON_IN + 2 * m_;           \
            sv0[0] = *(const float2*)(xr_);                                    \
            sv0[1] = *(const float2*)(xr_ + CHW);                              \
            sv0[2] = *(const float2*)(xr_ + 2 * CHW);                          \
            sv0[3] = *(const float2*)(xr_ + 3 * CHW);                          \
        }                                                                      \
        {   const int idx_ = tid + 256;                                        \
            const int rr_ = idx_ >= 360;                                       \
            const int m_  = idx_ - 360 * rr_;                                  \
            const int row_ = min((R0) + rr_, hl);                              \
            const float* xr_ = xb + (size_t)row_ * NLON_IN + 2 * m_;           \
            sv1[0] = *(const float2*)(xr_);                                    \
            sv1[1] = *(const float2*)(xr_ + CHW);                              \
            sv1[2] = *(const float2*)(xr_ + 2 * CHW);                          \
            sv1[3] = *(const float2*)(xr_ + 3 * CHW);                          \
        }                                                                      \
        if (tid < 208) {                                                       \
            const int m_  = tid + 512 - 360;                                   \
            const int row_ = min((R0) + 1, hl);                                \
            const float* xr_ = xb + (size_t)row_ * NLON_IN + 2 * m_;           \
            sv2[0] = *(const float2*)(xr_);                                    \
            sv2[1] = *(const float2*)(xr_ + CHW);                              \
            sv2[2] = *(const float2*)(xr_ + 2 * CHW);                          \
            sv2[3] = *(const float2*)(xr_ + 3 * CHW);                          \
        }                                                                      \
    }

#define WRITEW()                                                               \
    {                                                                          \
        {   const int idx_ = tid;                                              \
            const int rr_ = idx_ >= 360;                                       \
            const int m_  = idx_ - 360 * rr_;                                  \
            const float4 ev_ = {sv0[0].x, sv0[1].x, sv0[2].x, sv0[3].x};       \
            const float4 ov_ = {sv0[0].y, sv0[1].y, sv0[2].y, sv0[3].y};       \
            ldsx[2 * rr_ + 0][m_] = ev_;                                       \
            ldsx[2 * rr_ + 1][m_] = ov_;                                       \
            if (m_ < MIRROR) {                                                 \
                ldsx[2 * rr_ + 0][NLON_OUT + m_] = ev_;                        \
                ldsx[2 * rr_ + 1][NLON_OUT + m_] = ov_;                        \
            }                                                                  \
        }                                                                      \
        {   const int idx_ = tid + 256;                                        \
            const int rr_ = idx_ >= 360;                                       \
            const int m_  = idx_ - 360 * rr_;                                  \
            const float4 ev_ = {sv1[0].x, sv1[1].x, sv1[2].x, sv1[3].x};       \
            const float4 ov_ = {sv1[0].y, sv1[1].y, sv1[2].y, sv1[3].y};       \
            ldsx[2 * rr_ + 0][m_] = ev_;                                       \
            ldsx[2 * rr_ + 1][m_] = ov_;                                       \
            if (m_ < MIRROR) {                                                 \
                ldsx[2 * rr_ + 0][NLON_OUT + m_] = ev_;                        \
                ldsx[2 * rr_ + 1][NLON_OUT + m_] = ov_;                        \
            }                                                                  \
        }                                                                      \
        if (tid < 208) {                                                       \
            const int m_ = tid + 512 - 360;                                    \
            const float4 ev_ = {sv2[0].x, sv2[1].x, sv2[2].x, sv2[3].x};       \
            const float4 ov_ = {sv2[0].y, sv2[1].y, sv2[2].y, sv2[3].y};       \
            ldsx[2][m_] = ev_;                                                 \
            ldsx[3][m_] = ov_;                                                 \
            if (m_ < MIRROR) {                                                 \
                ldsx[2][NLON_OUT + m_] = ev_;                                  \
                ldsx[3][NLON_OUT + m_] = ov_;                                  \
            }                                                                  \
        }                                                                      \
    }

    if (hb <= hl) {
        LOADW(hb);                              // prologue: first window in flight
        for (int r0 = hb; r0 <= hl; r0 += MAXR) {
            const int rn = min(MAXR, hl - r0 + 1);
            __syncthreads();                    // readers of previous window done
            WRITEW();                           // vmcnt wait hidden under prev compute
            if (r0 + MAXR <= hl) LOADW(r0 + MAXR);
            __syncthreads();                    // LDS ready
            // ---- compute window ----
            for (int r = 0; r < rn; ++r) {
                const int j = (r0 + r) - hb;
                if (j < 0 || j >= PH - 1) continue;
                if ((j & 1) != wpair) continue;  // wave-uniform
                const int idx = s * PH + j;
                const int a = ptrh[idx], b = ptrh[idx + 1];
                if (a >= b) continue;
                const int rp0 = (j & 1) * 2;
                if (flags[idx]) {                // constant-val full row: cf*rowsum
                    float4 v = {0.f, 0.f, 0.f, 0.f};
                    for (int m = lane; m < NLON_OUT; m += 64) {
                        const float4 u0 = ldsx[rp0][m], u1 = ldsx[rp0 + 1][m];
                        v.x += u0.x + u1.x; v.y += u0.y + u1.y;
                        v.z += u0.z + u1.z; v.w += u0.w + u1.w;
                    }
#pragma unroll
                    for (int o = 32; o >= 1; o >>= 1) {
                        v.x += __shfl_xor(v.x, o); v.y += __shfl_xor(v.y, o);
                        v.z += __shfl_xor(v.z, o); v.w += __shfl_xor(v.w, o);
                    }
                    const float cf = cfb[a];
                    a0l.x = fmaf(cf, v.x, a0l.x); a0l.y = fmaf(cf, v.y, a0l.y);
                    a0h.x = fmaf(cf, v.z, a0h.x); a0h.y = fmaf(cf, v.w, a0h.y);
                    a1l.x = fmaf(cf, v.x, a1l.x); a1l.y = fmaf(cf, v.y, a1l.y);
                    a1h.x = fmaf(cf, v.z, a1h.x); a1h.y = fmaf(cf, v.w, a1h.y);
                    a2l.x = fmaf(cf, v.x, a2l.x); a2l.y = fmaf(cf, v.y, a2l.y);
                    a2h.x = fmaf(cf, v.z, a2h.x); a2h.y = fmaf(cf, v.w, a2h.y);
                    continue;
                }
                const int rc = runcnt[idx];
                for (int rr = 0; rr < rc; ++rr) {
                    const uint2 R = runslab[a + rr];
                    const int e0  = __builtin_amdgcn_readfirstlane((int)R.x);
                    const int y   = __builtin_amdgcn_readfirstlane((int)R.y);
                    const int s0A = y & 511;
                    const int odd = (y >> 9) & 1;
                    const int len = y >> 11;
                    int qA = s0A - p0 - 2; qA += (qA >> 31) & NLON_OUT;
                    const char* baseA = lb + (size_t)(rp0 + odd) * ROWB + ((size_t)qA << 4);
                    const char* baseB = lb + (size_t)(rp0 + (odd ^ 1)) * ROWB
                                           + ((size_t)(qA + odd) << 4);
                    const float* cfp = cfb + e0;
                    int i = 0;
                    if (len >= 8) {
                        v2f A0l = *(const v2f*)(baseA +  0), A0h = *(const v2f*)(baseA +  8);
                        v2f A1l = *(const v2f*)(baseA + 16), A1h = *(const v2f*)(baseA + 24);
                        v2f A2l = *(const v2f*)(baseA + 32), A2h = *(const v2f*)(baseA + 40);
                        v2f B0l = *(const v2f*)(baseB +  0), B0h = *(const v2f*)(baseB +  8);
                        v2f B1l = *(const v2f*)(baseB + 16), B1h = *(const v2f*)(baseB + 24);
                        v2f B2l = *(const v2f*)(baseB + 32), B2h = *(const v2f*)(baseB + 40);
                        v2f A3l, A3h, B3l, B3h;
                        const char* ldA = baseA + 48;
                        const char* ldB = baseB + 48;
                        for (; i + 8 <= len; i += 8) {
                            float cs; v2f c;
                            A3l = *(const v2f*)(ldA); A3h = *(const v2f*)(ldA + 8); ldA += 16;
                            cs = cfp[i + 0]; c = (v2f){cs, cs};
                            PKF(a2l, A0l, c); PKF(a2h, A0h, c);
                            PKF(a1l, A1l, c); PKF(a1h, A1h, c);
                            PKF(a0l, A2l, c); PKF(a0h, A2h, c);
                            B3l = *(const v2f*)(ldB); B3h = *(const v2f*)(ldB + 8); ldB += 16;
                            cs = cfp[i + 1]; c = (v2f){cs, cs};
                            PKF(a2l, B0l, c); PKF(a2h, B0h, c);
                            PKF(a1l, B1l, c); PKF(a1h, B1h, c);
                            PKF(a0l, B2l, c); PKF(a0h, B2h, c);
                            A0l = *(const v2f*)(ldA); A0h = *(const v2f*)(ldA + 8); ldA += 16;
                            cs = cfp[i + 2]; c = (v2f){cs, cs};
                            PKF(a2l, A1l, c); PKF(a2h, A1h, c);
                            PKF(a1l, A2l, c); PKF(a1h, A2h, c);
                            PKF(a0l, A3l, c); PKF(a0h, A3h, c);
                            B0l = *(const v2f*)(ldB); B0h = *(const v2f*)(ldB + 8); ldB += 16;
                            cs = cfp[i + 3]; c = (v2f){cs, cs};
                            PKF(a2l, B1l, c); PKF(a2h, B1h, c);
                            PKF(a1l, B2l, c); PKF(a1h, B2h, c);
                            PKF(a0l, B3l, c); PKF(a0h, B3h, c);
                            A1l = *(const v2f*)(ldA); A1h = *(const v2f*)(ldA + 8); ldA += 16;
                            cs = cfp[i + 4]; c = (v2f){cs, cs};
                            PKF(a2l, A2l, c); PKF(a2h, A2h, c);
                            PKF(a1l, A3l, c); PKF(a1h, A3h, c);
                            PKF(a0l, A0l, c); PKF(a0h, A0h, c);
                            B1l = *(const v2f*)(ldB); B1h = *(const v2f*)(ldB + 8); ldB += 16;
                            cs = cfp[i + 5]; c = (v2f){cs, cs};
                            PKF(a2l, B2l, c); PKF(a2h, B2h, c);
                            PKF(a1l, B3l, c); PKF(a1h, B3h, c);
                            PKF(a0l, B0l, c); PKF(a0h, B0h, c);
                            A2l = *(const v2f*)(ldA); A2h = *(const v2f*)(ldA + 8); ldA += 16;
                            cs = cfp[i + 6]; c = (v2f){cs, cs};
                            PKF(a2l, A3l, c); PKF(a2h, A3h, c);
                            PKF(a1l, A0l, c); PKF(a1h, A0h, c);
                            PKF(a0l, A1l, c); PKF(a0h, A1h, c);
                            B2l = *(const v2f*)(ldB); B2h = *(const v2f*)(ldB + 8); ldB += 16;
                            cs = cfp[i + 7]; c = (v2f){cs, cs};
                            PKF(a2l, B3l, c); PKF(a2h, B3h, c);
                            PKF(a1l, B0l, c); PKF(a1h, B0h, c);
                            PKF(a0l, B1l, c); PKF(a0h, B1h, c);
                        }
                    }
                    for (; i < len; ++i) {       // tail / short runs
                        const int m = i >> 1;
                        const char* bp = (i & 1) ? (baseB + ((size_t)m << 4))
                                                 : (baseA + ((size_t)m << 4));
                        const float cs = cfp[i]; const v2f c = (v2f){cs, cs};
                        const v2f w0l = *(const v2f*)(bp +  0), w0h = *(const v2f*)(bp +  8);
                        const v2f w1l = *(const v2f*)(bp + 16), w1h = *(const v2f*)(bp + 24);
                        const v2f w2l = *(const v2f*)(bp + 32), w2h = *(const v2f*)(bp + 40);
                        PKF(a2l, w0l, c); PKF(a2h, w0h, c);
                        PKF(a1l, w1l, c); PKF(a1h, w1h, c);
                        PKF(a0l, w2l, c); PKF(a0h, w2h, c);
                    }
                }
            }
        }
    }

    // ---- combine pair-1 into pair-0, store (accbuf overlays ldsx) ----
    __syncthreads();
    if (wpair == 1 && pairlane < 120) {
        accbuf[pid][0] = a0l; accbuf[pid][1] = a0h;
        accbuf[pid][2] = a1l; accbuf[pid][3] = a1h;
        accbuf[pid][4] = a2l; accbuf[pid][5] = a2h;
    }
    __syncthreads();
    if (wpair == 0 && pairlane < 120) {
        a0l += accbuf[pid][0]; a0h += accbuf[pid][1];
        a1l += accbuf[pid][2]; a1h += accbuf[pid][3];
        a2l += accbuf[pid][4]; a2h += accbuf[pid][5];
        const size_t cs_ = (size_t)NSEG * NLON_OUT;
        const size_t ob  = ((size_t)bc0 * NSEG + s) * NLON_OUT + p0;
        out[ob]              = a0l.x; out[ob + 1]              = a1l.x; out[ob + 2]              = a2l.x;
        out[ob + cs_]        = a0l.y; out[ob + cs_ + 1]        = a1l.y; out[ob + cs_ + 2]        = a2l.y;
        out[ob + 2 * cs_]    = a0h.x; out[ob + 2 * cs_ + 1]    = a1h.x; out[ob + 2 * cs_ + 2]    = a2h.x;
        out[ob + 3 * cs_]    = a0h.y; out[ob + 3 * cs_ + 1]    = a1h.y; out[ob + 3 * cs_ + 2]    = a2h.y;
    }
#undef LOADW
#undef WRITEW
}

// ---------------- fallback (tiny ws) ----------------

__global__ void segptr_kernel(const int* __restrict__ seg, int nnz, int* __restrict__ ptr) {
    int s = blockIdx.x * blockDim.x + threadIdx.x;
    if (s > NSEG) return;
    if (s == NSEG) { ptr[NSEG] = nnz; return; }
    int lo = 0, hi = nnz;
    while (lo < hi) { int m = (lo + hi) >> 1; if (seg[m] < s) lo = m + 1; else hi = m; }
    ptr[s] = lo;
}

__global__ __launch_bounds__(384) void disco_simple_kernel(
    const float* __restrict__ x, const float* __restrict__ qw,
    const int* __restrict__ lat, const int* __restrict__ lon,
    const float* __restrict__ val, const int* __restrict__ ptr,
    float* __restrict__ out)
{
    const int p = threadIdx.x;
    if (p >= NLON_OUT) return;
    const int kt = blockIdx.x, bc0 = blockIdx.y * 8;
    const int e0 = ptr[kt], e1 = ptr[kt + 1];
    float acc[8];
#pragma unroll
    for (int g = 0; g < 8; ++g) acc[g] = 0.0f;
    const int pw = 2 * p + 2;
    const float* xb = x + (size_t)bc0 * CHW;
    for (int e = e0; e < e1; ++e) {
        const int h = lat[e], w = lon[e];
        const float cf = val[e] * qw[h];
        int col = w - pw; if (col < 0) col += NLON_IN;
        const float* src = xb + h * NLON_IN + col;
#pragma unroll
        for (int g = 0; g < 8; ++g) acc[g] = fmaf(cf, src[(size_t)g * CHW], acc[g]);
    }
    const size_t ob = ((size_t)bc0 * NSEG + kt) * NLON_OUT + p;
#pragma unroll
    for (int g = 0; g < 8; ++g) out[ob + (size_t)g * NSEG * NLON_OUT] = acc[g];
}

// ---------------- launcher ----------------

extern "C" void kernel_launch(void* const* d_in, const int* in_sizes, int n_in,
                              void* d_out, int out_size, void* d_ws, size_t ws_size,
                              hipStream_t stream)
{
    const float* x   = (const float*)d_in[0];   // [2,64,360,720] f32
    const float* qw  = (const float*)d_in[1];   // [360,1] f32
    const int*   seg = (const int*)  d_in[2];   // [nnz] i32 sorted asc
    const int*   lat = (const int*)  d_in[3];
    const int*   lon = (const int*)  d_in[4];
    const float* val = (const float*)d_in[5];
    const int    nnz = in_sizes[2];
    const int    nnzpad = (nnz + 3) & ~3;

    char* w = (char*)d_ws;
    size_t off = 0;
    int* ptrh   = (int*)(w + off); off += (size_t)NSEG * PH * 4;   // 21600
    int* hbase  = (int*)(w + off); off += NSEG * 4;
    int* hlast  = (int*)(w + off); off += NSEG * 4;
    int* flags  = (int*)(w + off); off += (size_t)NSEG * PH * 4;
    int* runcnt = (int*)(w + off); off += (size_t)NSEG * PH * 4;
    float* cfb  = (float*)(w + off); off += (size_t)nnzpad * 4;
    off = (off + 7) & ~(size_t)7;
    uint2* runslab = (uint2*)(w + off); off += (size_t)nnz * 8;

    if (ws_size < off) {                         // tiny ws: slow-but-correct path
        int* ptr = (int*)d_ws;
        segptr_kernel<<<(NSEG + 1 + 255) / 256, 256, 0, stream>>>(seg, nnz, ptr);
        dim3 grid(NSEG, BCTOT / 8);
        disco_simple_kernel<<<grid, 384, 0, stream>>>(x, qw, lat, lon, val, ptr,
                                                      (float*)d_out);
        return;
    }

    prep1_kernel<<<(NSEG * PH + 255) / 256, 256, 0, stream>>>(seg, lat, val, nnz,
                                                              ptrh, hbase, hlast, flags);
    cf_kernel<<<(nnz + 255) / 256, 256, 0, stream>>>(lat, val, qw, nnz, cfb);
    runs_kernel<<<(NSEG * PH + 3) / 4, 256, 0, stream>>>(lon, ptrh, flags,
                                                         runcnt, runslab);

    dim3 grid(NBCG, NLAT_OUT, KSIZE);
    disco_kernel<<<grid, NTHREADS, 0, stream>>>(x, cfb, runslab, runcnt,
                                                ptrh, hbase, hlast, flags,
                                                (float*)d_out);
}